// Round 5
// baseline (213.720 us; speedup 1.0000x reference)
//
#include <hip/hip_runtime.h>

// Native clang vector: layout-identical to float4, accepted by nontemporal builtins.
typedef float vfloat4 __attribute__((ext_vector_type(4)));

namespace {
constexpr int kB = 8;
constexpr int kL = 4096;
constexpr int kD = 768;
constexpr int kW = 12;           // ATTN_WIDTH
constexpr int kHalo = kW - 1;    // 11
constexpr float kEps = 1e-7f;

// K1: u = x @ Wa (fp64)
constexpr int kRowsPerBlockU = 16;               // 4 waves x 4 rows
constexpr int kGridU = kB * kL / kRowsPerBlockU; // 2048

// K2: banded v — barrier-free, LDS-free
constexpr int kT2 = 8;                           // output rows per block
constexpr int kRing = kT2 + kHalo;               // 19 rows per block
constexpr int kThreads2 = 192;                   // 192*4 == kD
constexpr int kChunks2 = kL / kT2;               // 512
constexpr int kGridV = kB * kChunks2;            // 4096
}

// ---------------- K1: u[b,l] = sum_d x[b,l,d] * Wa[d]  (fp64 accum) -------
// Pure streaming matvec: 12 independent dwordx4 loads per wave, no barriers.
// fp64 mandatory: denom = u*wsum+eps cancels to ~7e-5 at the worst row.
// Identical to the round-0 baseline kernel (workspace: u only, 256 KB).
__global__ __launch_bounds__(256, 4) void compute_u_kernel(
    const float* __restrict__ x, const float* __restrict__ Wa,
    double* __restrict__ u) {
  const int lane = threadIdx.x & 63;
  const int wv = threadIdx.x >> 6;  // 0..3
  const int rg0 = blockIdx.x * kRowsPerBlockU + wv * 4;  // 4 rows per wave

  vfloat4 w[3];
#pragma unroll
  for (int k = 0; k < 3; ++k)
    w[k] = *(const vfloat4*)(Wa + 4 * lane + 256 * k);

  // Issue all 12 loads before any math: deep memory pipeline.
  vfloat4 xv[4][3];
#pragma unroll
  for (int q = 0; q < 4; ++q)
#pragma unroll
    for (int k = 0; k < 3; ++k)
      xv[q][k] = *(const vfloat4*)(x + (size_t)(rg0 + q) * kD + 4 * lane + 256 * k);

  double acc[4];
#pragma unroll
  for (int q = 0; q < 4; ++q) {
    double p = 0.0;
#pragma unroll
    for (int k = 0; k < 3; ++k) {
      p += (double)xv[q][k].x * (double)w[k].x + (double)xv[q][k].y * (double)w[k].y +
           (double)xv[q][k].z * (double)w[k].z + (double)xv[q][k].w * (double)w[k].w;
    }
    acc[q] = p;
  }
#pragma unroll
  for (int q = 0; q < 4; ++q) {
#pragma unroll
    for (int s = 32; s >= 1; s >>= 1) acc[q] += __shfl_xor(acc[q], s, 64);
  }
  if (lane == 0) {
#pragma unroll
    for (int q = 0; q < 4; ++q) u[rg0 + q] = acc[q];
  }
}

// ---------------- K2: v_i = scale_i * sum_{j} uf_{i-j} x_{i-j} ------------
// Barrier-free, LDS-free. All 19 x-row loads issued upfront; uf and scale
// are derived in-block from wave-uniform (L2-hot) fp64 reads of u, so no
// extra workspace arrays and no extra launch. Waves fully independent ->
// TLP hides the load-burst latency the round-3 phase chain serialized on.
__global__ __launch_bounds__(kThreads2, 3) void banded_v_kernel(
    const float* __restrict__ x, const double* __restrict__ u,
    float* __restrict__ out) {
  const int blk = blockIdx.x;
  const int b = blk / kChunks2;
  const int i0 = (blk % kChunks2) * kT2;
  const float* xb = x + (size_t)b * kL * kD;
  float* ob = out + (size_t)b * kL * kD;
  const double* ub = u + (size_t)b * kL;
  const int tid = threadIdx.x;
  const int lane = tid & 63;
  const int c0 = 4 * tid;

  // ---- x burst first: 19 independent dwordx4, nothing depends on them yet.
  vfloat4 xr[kRing];
  float ufr[kRing];
  if (i0 >= kHalo) {
    // Hot path (4080/4096 blocks): no guards.
#pragma unroll
    for (int r = 0; r < kRing; ++r)
      xr[r] = *(const vfloat4*)(xb + (size_t)(i0 - kHalo + r) * kD + c0);
#pragma unroll
    for (int r = 0; r < kRing; ++r)
      ufr[r] = (float)ub[i0 - kHalo + r];  // uniform, L2-hot, same cast as ever
  } else {
    // First two chunks of each batch: rows < 0 are zero (padded cumsum).
#pragma unroll
    for (int r = 0; r < kRing; ++r) {
      const int row = i0 - kHalo + r;
      vfloat4 v = {0.f, 0.f, 0.f, 0.f};
      float uu = 0.0f;
      if (row >= 0) {
        v = *(const vfloat4*)(xb + (size_t)row * kD + c0);
        uu = (float)ub[row];
      }
      xr[r] = v;
      ufr[r] = uu;
    }
  }

  // ---- scale: one row per lane (lane&7), fp64 ascending-j window, then
  // width-8 shfl broadcast. Identical arithmetic to all passing rounds.
  {
    const int myt = lane & 7;
    const int il = i0 + myt;  // within-batch row, always >= 0
    double wsum = 0.0;
#pragma unroll
    for (int k = 0; k < kW; ++k) {
      const int j = il - kHalo + k;
      if (j >= 0) wsum += ub[j];
    }
    const double uu = ub[il];
    const float msc = (float)(uu / (uu * wsum + (double)kEps));
    float sc[kT2];
#pragma unroll
    for (int t = 0; t < kT2; ++t) sc[t] = __shfl(msc, t, 8);

    // ---- banded accumulate, entirely register-resident, fp32.
#pragma unroll
    for (int t = 0; t < kT2; ++t) {
      vfloat4 acc = {0.f, 0.f, 0.f, 0.f};
#pragma unroll
      for (int j = 0; j < kW; ++j) {
        const int r = kHalo + t - j;  // static after unroll
        const float uu2 = ufr[r];
        const vfloat4 xv = xr[r];
        acc.x += uu2 * xv.x; acc.y += uu2 * xv.y;
        acc.z += uu2 * xv.z; acc.w += uu2 * xv.w;
      }
      const float s = sc[t];
      vfloat4 o = {s * acc.x, s * acc.y, s * acc.z, s * acc.w};
      // output never re-read: don't pollute L2/L3 (keep x resident)
      __builtin_nontemporal_store(o, (vfloat4*)(ob + (size_t)(i0 + t) * kD + c0));
    }
  }
}

extern "C" void kernel_launch(void* const* d_in, const int* in_sizes, int n_in,
                              void* d_out, int out_size, void* d_ws, size_t ws_size,
                              hipStream_t stream) {
  const float* x = (const float*)d_in[0];
  const float* Wa = (const float*)d_in[1];
  float* out = (float*)d_out;
  double* u = (double*)d_ws;  // 32768 * 8 B = 256 KB — same as all passing rounds
  (void)ws_size;

  compute_u_kernel<<<kGridU, 256, 0, stream>>>(x, Wa, u);
  banded_v_kernel<<<kGridV, kThreads2, 0, stream>>>(x, u, out);
}

// Round 6
// 196.474 us; speedup vs baseline: 1.0878x; 1.0878x over previous
//
#include <hip/hip_runtime.h>

// Native clang vector: layout-identical to float4, accepted by nontemporal builtins.
typedef float vfloat4 __attribute__((ext_vector_type(4)));

namespace {
constexpr int kB = 8;
constexpr int kL = 4096;
constexpr int kD = 768;
constexpr int kW = 12;           // ATTN_WIDTH
constexpr int kHalo = kW - 1;    // 11
constexpr float kEps = 1e-7f;

constexpr int kT = 16;                   // output rows per chunk
constexpr int kC = 2;                    // chunks per block
constexpr int kS = kT * kC;              // 32-row strip per block
constexpr int kRing = kT + kHalo;        // 27 register ring slots
constexpr int kThreads = 192;            // 192*4 == kD
constexpr int kStrips = kL / kS;         // 128 strips per batch
constexpr int kGrid = kB * kStrips;      // 1024 -> 4 blocks/CU
constexpr int kGroups = kThreads / 4;    // 48 four-lane column groups
constexpr int kUMask = 31;               // 32-slot LDS u-ring
}

__device__ __forceinline__ double dot4d(const vfloat4 a, const vfloat4 w) {
  return (double)a.x * (double)w.x + (double)a.y * (double)w.y +
         (double)a.z * (double)w.z + (double)a.w * (double)w.w;
}

// Raw barrier: LDS ordering only. __syncthreads() would emit
// s_waitcnt vmcnt(0) lgkmcnt(0) — draining ALL in-flight global loads AND
// nontemporal stores at every barrier (r3's stall). The only cross-thread
// hazards here are LDS, so lgkmcnt(0) + s_barrier is sufficient; global
// memory ops stay in flight across the barrier (T3/T4 pattern).
__device__ __forceinline__ void lds_barrier() {
  asm volatile("s_waitcnt lgkmcnt(0)" ::: "memory");
  __builtin_amdgcn_s_barrier();
}

// Persistent 32-row strip per block; 27-slot register ring; u reduced via
// LDS partials + wave-0 finish; scale computed in the same wave-0 region via
// in-wave shuffles (no extra barrier). All barriers are lgkmcnt-only.
// XCD mapping: batch = bid&7 (round-robin dispatch => one batch per XCD),
// strip = bid>>3 => consecutive strips share halo rows in the same L2.
//
// Numerics: identical fp64 summation orders to the passing r3 kernel
// (per-thread dot4, 4-lane butterfly, 12-partial ascending sums + butterfly,
// ascending-k wsum, uu/(uu*wsum+eps) in fp64).
__global__ __launch_bounds__(kThreads, 3) void banded_strip_kernel(
    const float* __restrict__ x, const float* __restrict__ Wa,
    float* __restrict__ out) {
  // +1 double pad: stage-2 rows 49*8 B apart -> 2-way conflict max (free).
  __shared__ double s_part[kRing][kGroups + 1];  // 10.6 KB
  __shared__ double s_ud[kUMask + 1];
  __shared__ float s_uf[kUMask + 1];
  __shared__ float s_scale[kT];

  const int bid = blockIdx.x;
  const int b = bid & 7;             // batch == XCD under round-robin dispatch
  const int s0 = (bid >> 3) * kS;    // strip start row within batch
  const float* xb = x + (size_t)b * kL * kD;
  float* ob = out + (size_t)b * kL * kD;
  const int tid = threadIdx.x;
  const int c0 = 4 * tid;
  const vfloat4 w4 = *(const vfloat4*)(Wa + c0);

  // ---- Prologue: ring slots 0..26 = rows s0-11 .. s0+15.
  vfloat4 xr[kRing];
  if (s0 >= kHalo) {
#pragma unroll
    for (int r = 0; r < kRing; ++r)
      xr[r] = *(const vfloat4*)(xb + (size_t)(s0 - kHalo + r) * kD + c0);
  } else {
    // First strip of each batch: rows < 0 are zero (padded cumsum semantics;
    // also makes their u exactly 0.0, matching the reference skip).
#pragma unroll
    for (int r = 0; r < kRing; ++r) {
      const int row = s0 - kHalo + r;
      vfloat4 v = {0.f, 0.f, 0.f, 0.f};
      if (row >= 0) v = *(const vfloat4*)(xb + (size_t)row * kD + c0);
      xr[r] = v;
    }
  }

  // u-partials for all 27 prologue rows: fp64 dot4 + 4-lane butterfly.
#pragma unroll
  for (int r = 0; r < kRing; ++r) {
    double p = dot4d(xr[r], w4);
    p += __shfl_xor(p, 1, 64);
    p += __shfl_xor(p, 2, 64);
    if ((tid & 3) == 0) s_part[r][tid >> 2] = p;
  }
  lds_barrier();

  // ---- Wave-0 finish: rows 0..15 (ua) then rows 16..26 (ub2), then scale
  // for chunk 0 gathered in-register — one barrier total for all of it.
  if (tid < 64) {
    const int r = tid >> 2, q = tid & 3;
    double ua = 0.0;
#pragma unroll
    for (int g = 0; g < 12; ++g) ua += s_part[r][q * 12 + g];
    ua += __shfl_xor(ua, 1, 64);
    ua += __shfl_xor(ua, 2, 64);
    const int r2 = (r + kT < kRing) ? r + kT : kRing - 1;  // clamp lanes 44..63
    double ub2 = 0.0;
#pragma unroll
    for (int g = 0; g < 12; ++g) ub2 += s_part[r2][q * 12 + g];
    ub2 += __shfl_xor(ub2, 1, 64);
    ub2 += __shfl_xor(ub2, 2, 64);
    if (q == 0) {
      s_ud[r] = ua;
      s_uf[r] = (float)ua;
      if (r < kRing - kT) { s_ud[kT + r] = ub2; s_uf[kT + r] = (float)ub2; }
    }
    // scale_t, t = tid (<16): window u[t..t+11], ascending adds (== r3 order).
    double wsum = 0.0, last = 0.0;
#pragma unroll
    for (int k = 0; k < kW; ++k) {
      const int l = tid + k;  // relevant for tid < 16 only
      const double va = __shfl(ua, (4 * l) & 63, 64);
      const double vb = __shfl(ub2, (4 * (l - kT)) & 63, 64);
      const double v = (l < kT) ? va : vb;
      wsum += v;
      if (k == kW - 1) last = v;
    }
    if (tid < kT) s_scale[tid] = (float)(last / (last * wsum + (double)kEps));
  }
  lds_barrier();

#pragma unroll
  for (int c = 0; c < kC; ++c) {
    // ---- Phase B chunk c; prefetch chunk c+1 rows into freed ring slots.
    // Prefetch loads and nt-stores issued here stay in flight across the
    // lgkmcnt-only barriers below.
#pragma unroll
    for (int t = 0; t < kT; ++t) {
      vfloat4 acc = {0.f, 0.f, 0.f, 0.f};
#pragma unroll
      for (int j = 0; j < kW; ++j) {
        const int l = kT * c + t + kHalo - j;  // block-local row
        const float uu = s_uf[l & kUMask];     // broadcast read
        const vfloat4 xv = xr[l % kRing];      // static after unroll
        acc.x += uu * xv.x; acc.y += uu * xv.y;
        acc.z += uu * xv.z; acc.w += uu * xv.w;
      }
      const float s = s_scale[t];
      vfloat4 o = {s * acc.x, s * acc.y, s * acc.z, s * acc.w};
      // output never re-read: don't pollute L2/L3 (keep x resident)
      __builtin_nontemporal_store(o, (vfloat4*)(ob + (size_t)(s0 + kT * c + t) * kD + c0));
      if (c + 1 < kC) {
        // slot (kT*c+t)%27 was last read by THIS output; refill with the
        // next-chunk row (consumed by the partials right below).
        const int lnew = kRing + kT * c + t;   // row s0 - 11 + lnew
        xr[lnew % kRing] =
            *(const vfloat4*)(xb + (size_t)(s0 - kHalo + lnew) * kD + c0);
      }
    }

    if (c + 1 < kC) {
      // u-partials for the 16 prefetched rows.
#pragma unroll
      for (int t = 0; t < kT; ++t) {
        const int lnew = kRing + kT * c + t;
        double p = dot4d(xr[lnew % kRing], w4);
        p += __shfl_xor(p, 1, 64);
        p += __shfl_xor(p, 2, 64);
        if ((tid & 3) == 0) s_part[t][tid >> 2] = p;
      }
      lds_barrier();

      // Wave-0 finish + scale for chunk c+1 (in-wave gather, one barrier).
      if (tid < 64) {
        const int r = tid >> 2, q = tid & 3;
        double uc = 0.0;
#pragma unroll
        for (int g = 0; g < 12; ++g) uc += s_part[r][q * 12 + g];
        uc += __shfl_xor(uc, 1, 64);
        uc += __shfl_xor(uc, 2, 64);
        const int lw = kRing + kT * c + r;  // local row of this new u
        if (q == 0) {
          s_ud[lw & kUMask] = uc;
          s_uf[lw & kUMask] = (float)uc;
        }
        // scale_t for chunk c+1: window l = kT*(c+1)+t .. +11; old rows from
        // s_ud (stable since the previous barrier; writes above touch only
        // slots (kRing+kT*c+r)&31, disjoint from the old window), new rows
        // from the in-wave uc just computed.
        double wsum = 0.0, last = 0.0;
#pragma unroll
        for (int k = 0; k < kW; ++k) {
          const int l = kT * (c + 1) + tid + k;
          const double vnew = __shfl(uc, (4 * (l - (kRing + kT * c))) & 63, 64);
          const double v = (l < kRing + kT * c) ? s_ud[l & kUMask] : vnew;
          wsum += v;
          if (k == kW - 1) last = v;
        }
        if (tid < kT) s_scale[tid] = (float)(last / (last * wsum + (double)kEps));
      }
      lds_barrier();
    }
  }
}

extern "C" void kernel_launch(void* const* d_in, const int* in_sizes, int n_in,
                              void* d_out, int out_size, void* d_ws, size_t ws_size,
                              hipStream_t stream) {
  const float* x = (const float*)d_in[0];
  const float* Wa = (const float*)d_in[1];
  float* out = (float*)d_out;
  (void)d_ws; (void)ws_size;

  banded_strip_kernel<<<kGrid, kThreads, 0, stream>>>(x, Wa, out);
}

// Round 9
// 195.015 us; speedup vs baseline: 1.0959x; 1.0075x over previous
//
#include <hip/hip_runtime.h>

// Native clang vector: layout-identical to float4, accepted by nontemporal builtins.
typedef float vfloat4 __attribute__((ext_vector_type(4)));

namespace {
constexpr int kB = 8;
constexpr int kL = 4096;
constexpr int kD = 768;
constexpr int kW = 12;           // ATTN_WIDTH
constexpr int kHalo = kW - 1;    // 11
constexpr float kEps = 1e-7f;

// K1: u = x @ Wa (fp64) — proven round-0/5 kernel, byte-identical.
constexpr int kRowsPerBlockU = 16;               // 4 waves x 4 rows
constexpr int kGridU = kB * kL / kRowsPerBlockU; // 2048

// K2: wave-autonomous banded stencil. No barriers, no LDS, no inline asm.
constexpr int kS = 32;                    // rows per wave-strip
constexpr int kSlots = 16;                // register ring slots (x, u)
constexpr int kSMask = kSlots - 1;
constexpr int kThirds = 3;                // 3 x 256 columns = 768
constexpr int kStripsPerB = kL / kS;      // 128
constexpr int kWavesK2 = kB * kStripsPerB * kThirds;  // 3072 waves
constexpr int kThreads2 = 256;            // 4 fully independent waves/block
constexpr int kGrid2 = kWavesK2 * 64 / kThreads2;     // 768 -> 3 blocks/CU
}

// ---------------- K1: u[b,l] = sum_d x[b,l,d] * Wa[d]  (fp64 accum) -------
// Pure streaming matvec: 12 independent dwordx4 loads per wave, no barriers.
// fp64 mandatory: denom = u*wsum+eps cancels to ~7e-5 at the worst row.
// Identical to the round-0/5 passing kernel (workspace: u only, 256 KB).
__global__ __launch_bounds__(256, 4) void compute_u_kernel(
    const float* __restrict__ x, const float* __restrict__ Wa,
    double* __restrict__ u) {
  const int lane = threadIdx.x & 63;
  const int wv = threadIdx.x >> 6;  // 0..3
  const int rg0 = blockIdx.x * kRowsPerBlockU + wv * 4;  // 4 rows per wave

  vfloat4 w[3];
#pragma unroll
  for (int k = 0; k < 3; ++k)
    w[k] = *(const vfloat4*)(Wa + 4 * lane + 256 * k);

  // Issue all 12 loads before any math: deep memory pipeline.
  vfloat4 xv[4][3];
#pragma unroll
  for (int q = 0; q < 4; ++q)
#pragma unroll
    for (int k = 0; k < 3; ++k)
      xv[q][k] = *(const vfloat4*)(x + (size_t)(rg0 + q) * kD + 4 * lane + 256 * k);

  double acc[4];
#pragma unroll
  for (int q = 0; q < 4; ++q) {
    double p = 0.0;
#pragma unroll
    for (int k = 0; k < 3; ++k) {
      p += (double)xv[q][k].x * (double)w[k].x + (double)xv[q][k].y * (double)w[k].y +
           (double)xv[q][k].z * (double)w[k].z + (double)xv[q][k].w * (double)w[k].w;
    }
    acc[q] = p;
  }
#pragma unroll
  for (int q = 0; q < 4; ++q) {
#pragma unroll
    for (int s = 32; s >= 1; s >>= 1) acc[q] += __shfl_xor(acc[q], s, 64);
  }
  if (lane == 0) {
#pragma unroll
    for (int q = 0; q < 4; ++q) u[rg0 + q] = acc[q];
  }
}

// ---------------- K2: wave-autonomous streaming banded stencil ------------
// Each wave owns (batch, 32-row strip, 256-col third); lane owns 4 cols.
// 16-slot register rings for x rows and u values; slot(r_local)=r_local&15.
// Steady state per output row:
//   1 dwordx4 x-load (prefetch distance 5) + u load + 48 fp32 FMA +
//   rolling fp64 wsum + fp64 scale + 1 nt-store.
// No __syncthreads, no LDS, no inline asm — WAR on ring slots is resolved
// by SSA renaming (full unroll, every index compile-time constant), and
// per-thread load->use ordering by compiler-inserted vmcnt waits.
//
// Numerics: weights uf = (float)u (same cast as all passing rounds); scale
// in fp64 with a rolling 12-wide window (reorder vs ascending re-sum is
// ~1e-16 relative — far below the fp32 sensitivity that mandated fp64).
__global__ __launch_bounds__(kThreads2, 3) void banded_stencil_kernel(
    const float* __restrict__ x, const double* __restrict__ u,
    float* __restrict__ out) {
  const int wid = (int)((blockIdx.x * kThreads2 + threadIdx.x) >> 6);
  const int lane = threadIdx.x & 63;
  const int b = wid / (kStripsPerB * kThirds);
  const int rem = wid % (kStripsPerB * kThirds);
  const int s = rem / kThirds;         // strip index within batch
  const int h = rem % kThirds;         // column third
  const int i0 = s * kS;               // first output row of the strip
  const float* xb = x + (size_t)b * kL * kD + 256 * h + 4 * lane;
  float* ob = out + (size_t)b * kL * kD + 256 * h + 4 * lane;
  const double* ubase = u + (size_t)b * kL;

  vfloat4 xr[kSlots];   // x rows, slot = r_local & 15 (r_local = row-(i0-11))
  double ud[kSlots];    // fp64 u, same slotting
  float uf[kSlots];     // fp32 u (band weights)

  // ---- Prologue: r_local 0..15 = rows i0-11 .. i0+4 (halo + 5 prefetch).
  if (i0 >= kHalo) {  // hot path: strips 1..127 of each batch
#pragma unroll
    for (int r = 0; r < kSlots; ++r)
      xr[r] = *(const vfloat4*)(xb + (size_t)(i0 - kHalo + r) * kD);
#pragma unroll
    for (int r = 0; r < kSlots; ++r) {
      const double du = ubase[i0 - kHalo + r];
      ud[r] = du;
      uf[r] = (float)du;
    }
  } else {  // strip 0: rows < 0 are zero (padded-cumsum semantics)
#pragma unroll
    for (int r = 0; r < kSlots; ++r) {
      const int row = i0 - kHalo + r;
      vfloat4 v = {0.f, 0.f, 0.f, 0.f};
      double du = 0.0;
      if (row >= 0) {
        v = *(const vfloat4*)(xb + (size_t)row * kD);
        du = ubase[row];
      }
      xr[r] = v;
      ud[r] = du;
      uf[r] = (float)du;
    }
  }

  // Initial partial window: sum of u over rows i0-11..i0-1 (ascending).
  double wsum_p = 0.0;
#pragma unroll
  for (int r = 0; r < kHalo; ++r) wsum_p += ud[r];

  // ---- Steady loop: 32 output rows, fully unrolled.
#pragma unroll
  for (int t = 0; t < kS; ++t) {
    const int r = kHalo + t;                 // r_local of output row i0+t
    const double uu = ud[r & kSMask];
    const double wsum = wsum_p + uu;         // ascending order at t=0 == ref
    const float sc = (float)(uu / (uu * wsum + (double)kEps));

    vfloat4 acc = {0.f, 0.f, 0.f, 0.f};
#pragma unroll
    for (int j = 0; j < kW; ++j) {
      const int rs = (r - j) & kSMask;       // static after unroll
      const float w = uf[rs];
      const vfloat4 xv = xr[rs];
      acc.x += w * xv.x; acc.y += w * xv.y;
      acc.z += w * xv.z; acc.w += w * xv.w;
    }
    vfloat4 o = {sc * acc.x, sc * acc.y, sc * acc.z, sc * acc.w};
    // output never re-read: don't pollute L2/L3 (keep x resident)
    __builtin_nontemporal_store(o, (vfloat4*)(ob + (size_t)(i0 + t) * kD));

    // Roll the window BEFORE the slot is overwritten by prefetch.
    wsum_p = wsum - ud[(r - kHalo) & kSMask];

    // Prefetch r_local = t+16 (row i0+5+t) into the slot just freed.
    // Needed 5 iterations from now. Always in-bounds: row >= 5, and the
    // last needed r_local is 42 (row i0+31 <= 4095) — no cross-batch reads.
    if (t + kSlots <= kS + kHalo - 1) {      // t <= 26
      const int row = i0 - kHalo + t + kSlots;
      xr[t & kSMask] = *(const vfloat4*)(xb + (size_t)row * kD);
      const double nu = ubase[row];
      ud[t & kSMask] = nu;
      uf[t & kSMask] = (float)nu;
    }
  }
}

extern "C" void kernel_launch(void* const* d_in, const int* in_sizes, int n_in,
                              void* d_out, int out_size, void* d_ws, size_t ws_size,
                              hipStream_t stream) {
  const float* x = (const float*)d_in[0];
  const float* Wa = (const float*)d_in[1];
  float* out = (float*)d_out;
  double* u = (double*)d_ws;  // 32768 * 8 B = 256 KB — same as all passing rounds
  (void)ws_size;

  compute_u_kernel<<<kGridU, 256, 0, stream>>>(x, Wa, u);
  banded_stencil_kernel<<<kGrid2, kThreads2, 0, stream>>>(x, u, out);
}